// Round 1
// baseline (860.317 us; speedup 1.0000x reference)
//
#include <hip/hip_runtime.h>
#include <cstdint>
#include <cstddef>

#define N_NODES 12000
#define N_EDGES 384000
#define NEG_SLOPE 0.2f

__device__ __forceinline__ float leaky(float v) { return v > 0.f ? v : NEG_SLOPE * v; }

// ---------------------------------------------------------------------------
// h = x @ W  (per-node row), plus alpha_src = h.a_src, alpha_dst = h.a_dst
// ---------------------------------------------------------------------------
template <int FIN, int FOUT>
__global__ __launch_bounds__(256) void node_linear(
    const float* __restrict__ x, const float* __restrict__ W,
    const float* __restrict__ a_src, const float* __restrict__ a_dst,
    float* __restrict__ h, float* __restrict__ as_, float* __restrict__ ad_) {
  __shared__ float Ws[FIN * FOUT];
  __shared__ float av[FOUT], dv[FOUT];
  for (int i = threadIdx.x; i < FIN * FOUT; i += blockDim.x) Ws[i] = W[i];
  if (threadIdx.x < FOUT) {
    av[threadIdx.x] = a_src[threadIdx.x];
    dv[threadIdx.x] = a_dst[threadIdx.x];
  }
  __syncthreads();
  const int node = blockIdx.x * blockDim.x + threadIdx.x;
  if (node >= N_NODES) return;
  float xr[FIN];
#pragma unroll
  for (int k = 0; k < FIN; ++k) xr[k] = x[node * FIN + k];
  float ssum = 0.f, dsum = 0.f;
#pragma unroll 1
  for (int c = 0; c < FOUT; ++c) {
    float acc = 0.f;
#pragma unroll
    for (int k = 0; k < FIN; ++k) acc += xr[k] * Ws[k * FOUT + c];
    h[node * FOUT + c] = acc;
    ssum += acc * av[c];
    dsum += acc * dv[c];
  }
  as_[node] = ssum;
  ad_[node] = dsum;
}

// ---------------------------------------------------------------------------
// CSR build: histogram of dst (incl. self-loops), exclusive scan, scatter src
// ---------------------------------------------------------------------------
__global__ __launch_bounds__(256) void histo_kernel(const int* __restrict__ dst,
                                                    int* __restrict__ deg) {
  const int i = blockIdx.x * blockDim.x + threadIdx.x;
  if (i >= N_EDGES + N_NODES) return;
  const int d = (i < N_EDGES) ? dst[i] : (i - N_EDGES);
  atomicAdd(&deg[d], 1);
}

__global__ __launch_bounds__(1024) void scan_kernel(const int* __restrict__ deg,
                                                    int* __restrict__ rowp) {
  __shared__ int sm[1024];
  __shared__ int carry;
  const int t = threadIdx.x;
  if (t == 0) carry = 0;
  __syncthreads();
  for (int base = 0; base < N_NODES; base += 1024) {
    const int idx = base + t;
    const int v = (idx < N_NODES) ? deg[idx] : 0;
    sm[t] = v;
    __syncthreads();
    int run = v;
    for (int off = 1; off < 1024; off <<= 1) {
      const int other = (t >= off) ? sm[t - off] : 0;
      __syncthreads();
      run += other;
      sm[t] = run;
      __syncthreads();
    }
    const int c = carry;
    if (idx < N_NODES) rowp[idx] = c + run - v;  // exclusive
    __syncthreads();
    if (t == 1023) carry = c + run;
    __syncthreads();
  }
  if (t == 0) rowp[N_NODES] = carry;
}

__global__ __launch_bounds__(256) void scatter_kernel(
    const int* __restrict__ src, const int* __restrict__ dst,
    const int* __restrict__ rowp, int* __restrict__ fill,
    int* __restrict__ esrc) {
  const int i = blockIdx.x * blockDim.x + threadIdx.x;
  if (i >= N_EDGES + N_NODES) return;
  int s, d;
  if (i < N_EDGES) {
    s = src[i];
    d = dst[i];
  } else {
    s = d = i - N_EDGES;
  }
  const int pos = rowp[d] + atomicAdd(&fill[d], 1);
  esrc[pos] = s;
}

// ---------------------------------------------------------------------------
// Per-dst-node segment softmax + weighted aggregation. One wave per node.
// out[v] = relu( (sum_e exp(leaky(as[src]+ad[v]) - m) * h[src]) / sum_e exp(...) + b )
// ---------------------------------------------------------------------------
template <int F>
__global__ __launch_bounds__(256) void gat_aggregate(
    const int* __restrict__ rowp, const int* __restrict__ esrc,
    const float* __restrict__ h, const float* __restrict__ as_,
    const float* __restrict__ ad_, const float* __restrict__ b,
    float* __restrict__ out) {
  const int wid = (blockIdx.x * blockDim.x + threadIdx.x) >> 6;
  const int lane = threadIdx.x & 63;
  if (wid >= N_NODES) return;
  const int start = rowp[wid], end = rowp[wid + 1];
  const float adv = ad_[wid];

  // pass 1: segment max (lanes stride edges)
  float m = -1e30f;
  for (int i = start + lane; i < end; i += 64) m = fmaxf(m, leaky(as_[esrc[i]] + adv));
#pragma unroll
  for (int off = 32; off > 0; off >>= 1) m = fmaxf(m, __shfl_xor(m, off));

  // pass 2: segment sum of exp
  float ssum = 0.f;
  for (int i = start + lane; i < end; i += 64) ssum += __expf(leaky(as_[esrc[i]] + adv) - m);
#pragma unroll
  for (int off = 32; off > 0; off >>= 1) ssum += __shfl_xor(ssum, off);
  const float inv = 1.0f / ssum;

  // pass 3: weighted accumulation; lanes 0..F-1 own output dims
  float acc = 0.f;
  for (int i = start; i < end; ++i) {
    const int s = esrc[i];               // uniform across wave -> broadcast
    const float w = __expf(leaky(as_[s] + adv) - m);
    if (lane < F) acc += w * h[s * F + lane];
  }
  if (lane < F) {
    const float o = acc * inv + b[lane];
    out[wid * F + lane] = o > 0.f ? o : 0.f;
  }
}

// ---------------------------------------------------------------------------
// Decoder: out = sigmoid(z @ z^T), z: [12000][40] f32. 128x128 tile per block,
// 256 threads, 8x8 outputs per thread. LDS tiles stored transposed [k][node].
// ---------------------------------------------------------------------------
__global__ __launch_bounds__(256) void decoder_kernel(const float* __restrict__ z,
                                                      float* __restrict__ out) {
  __shared__ float At[40][132];  // row stride 132 floats = 528 B (16B aligned)
  __shared__ float Bt[40][132];
  const int i0 = blockIdx.y * 128;
  const int j0 = blockIdx.x * 128;
  const int t = threadIdx.x;

  // stage 128 rows x 10 float4 per tile
  for (int u = t; u < 1280; u += 256) {
    const int row = u / 10;
    const int kq = u - row * 10;
    int ga = i0 + row;
    ga = ga < N_NODES ? ga : N_NODES - 1;
    const float4 va = *(const float4*)(z + ga * 40 + kq * 4);
    At[kq * 4 + 0][row] = va.x;
    At[kq * 4 + 1][row] = va.y;
    At[kq * 4 + 2][row] = va.z;
    At[kq * 4 + 3][row] = va.w;
    int gb = j0 + row;
    gb = gb < N_NODES ? gb : N_NODES - 1;
    const float4 vb = *(const float4*)(z + gb * 40 + kq * 4);
    Bt[kq * 4 + 0][row] = vb.x;
    Bt[kq * 4 + 1][row] = vb.y;
    Bt[kq * 4 + 2][row] = vb.z;
    Bt[kq * 4 + 3][row] = vb.w;
  }
  __syncthreads();

  const int tx = t & 15, ty = t >> 4;
  float acc[8][8] = {};
  for (int k = 0; k < 40; ++k) {
    float a[8], b[8];
    *(float4*)&a[0] = *(const float4*)&At[k][ty * 8];
    *(float4*)&a[4] = *(const float4*)&At[k][ty * 8 + 4];
    *(float4*)&b[0] = *(const float4*)&Bt[k][tx * 8];
    *(float4*)&b[4] = *(const float4*)&Bt[k][tx * 8 + 4];
#pragma unroll
    for (int r = 0; r < 8; ++r)
#pragma unroll
      for (int c = 0; c < 8; ++c) acc[r][c] += a[r] * b[c];
  }

#pragma unroll
  for (int r = 0; r < 8; ++r) {
    const int gi = i0 + ty * 8 + r;
    if (gi < N_NODES) {
      float o[8];
#pragma unroll
      for (int c = 0; c < 8; ++c) o[c] = 1.0f / (1.0f + __expf(-acc[r][c]));
      const int gj = j0 + tx * 8;
      float* dstp = out + (size_t)gi * N_NODES + gj;
      if (gj + 7 < N_NODES) {
        *(float4*)dstp = make_float4(o[0], o[1], o[2], o[3]);
        *(float4*)(dstp + 4) = make_float4(o[4], o[5], o[6], o[7]);
      } else {
#pragma unroll
        for (int c = 0; c < 8; ++c)
          if (gj + c < N_NODES) dstp[c] = o[c];
      }
    }
  }
}

// ---------------------------------------------------------------------------
extern "C" void kernel_launch(void* const* d_in, const int* in_sizes, int n_in,
                              void* d_out, int out_size, void* d_ws, size_t ws_size,
                              hipStream_t stream) {
  const float* x     = (const float*)d_in[0];
  const int*   ei    = (const int*)d_in[1];   // [2][E], int32 per harness contract
  const float* W1    = (const float*)d_in[2];
  const float* asrc1 = (const float*)d_in[3];
  const float* adst1 = (const float*)d_in[4];
  const float* b1    = (const float*)d_in[5];
  const float* W2    = (const float*)d_in[6];
  const float* asrc2 = (const float*)d_in[7];
  const float* adst2 = (const float*)d_in[8];
  const float* b2    = (const float*)d_in[9];
  float* out = (float*)d_out;

  // workspace layout (all 16B-aligned: counts divisible by 4)
  float* ws   = (float*)d_ws;
  float* h1   = ws;              // N*50
  float* out1 = h1 + 600000;     // N*50
  float* h2   = out1 + 600000;   // N*40
  float* z    = h2 + 480000;     // N*40
  float* as_  = z + 480000;      // N
  float* ad_  = as_ + 12000;     // N
  int* deg  = (int*)(ad_ + 12000);  // N
  int* rowp = deg + 12000;          // N+1
  int* fill = rowp + 12001;         // N
  int* esrc = fill + 12000;         // E+N

  const int* src = ei;
  const int* dst = ei + N_EDGES;

  hipMemsetAsync(deg, 0, N_NODES * sizeof(int), stream);
  hipMemsetAsync(fill, 0, N_NODES * sizeof(int), stream);

  const int eb = (N_EDGES + N_NODES + 255) / 256;
  histo_kernel<<<eb, 256, 0, stream>>>(dst, deg);
  scan_kernel<<<1, 1024, 0, stream>>>(deg, rowp);
  scatter_kernel<<<eb, 256, 0, stream>>>(src, dst, rowp, fill, esrc);

  const int nb = (N_NODES + 255) / 256;
  node_linear<40, 50><<<nb, 256, 0, stream>>>(x, W1, asrc1, adst1, h1, as_, ad_);
  gat_aggregate<50><<<3000, 256, 0, stream>>>(rowp, esrc, h1, as_, ad_, b1, out1);
  node_linear<50, 40><<<nb, 256, 0, stream>>>(out1, W2, asrc2, adst2, h2, as_, ad_);
  gat_aggregate<40><<<3000, 256, 0, stream>>>(rowp, esrc, h2, as_, ad_, b2, z);

  dim3 dgrid(94, 94);
  decoder_kernel<<<dgrid, 256, 0, stream>>>(z, out);
}

// Round 2
// 793.737 us; speedup vs baseline: 1.0839x; 1.0839x over previous
//
#include <hip/hip_runtime.h>
#include <cstdint>
#include <cstddef>

#define N_NODES 12000
#define N_EDGES 384000
#define NEG_SLOPE 0.2f

__device__ __forceinline__ float leaky(float v) { return v > 0.f ? v : NEG_SLOPE * v; }

// ---------------------------------------------------------------------------
// h = x @ W  (per-node row), plus alpha_src = h.a_src, alpha_dst = h.a_dst
// ---------------------------------------------------------------------------
template <int FIN, int FOUT>
__global__ __launch_bounds__(256) void node_linear(
    const float* __restrict__ x, const float* __restrict__ W,
    const float* __restrict__ a_src, const float* __restrict__ a_dst,
    float* __restrict__ h, float* __restrict__ as_, float* __restrict__ ad_) {
  __shared__ float Ws[FIN * FOUT];
  __shared__ float av[FOUT], dv[FOUT];
  for (int i = threadIdx.x; i < FIN * FOUT; i += blockDim.x) Ws[i] = W[i];
  if (threadIdx.x < FOUT) {
    av[threadIdx.x] = a_src[threadIdx.x];
    dv[threadIdx.x] = a_dst[threadIdx.x];
  }
  __syncthreads();
  const int node = blockIdx.x * blockDim.x + threadIdx.x;
  if (node >= N_NODES) return;
  float xr[FIN];
#pragma unroll
  for (int k = 0; k < FIN; ++k) xr[k] = x[node * FIN + k];
  float ssum = 0.f, dsum = 0.f;
#pragma unroll 1
  for (int c = 0; c < FOUT; ++c) {
    float acc = 0.f;
#pragma unroll
    for (int k = 0; k < FIN; ++k) acc += xr[k] * Ws[k * FOUT + c];
    h[node * FOUT + c] = acc;
    ssum += acc * av[c];
    dsum += acc * dv[c];
  }
  as_[node] = ssum;
  ad_[node] = dsum;
}

// ---------------------------------------------------------------------------
// CSR build: histogram of dst (incl. self-loops), exclusive scan, scatter src
// ---------------------------------------------------------------------------
__global__ __launch_bounds__(256) void histo_kernel(const int* __restrict__ dst,
                                                    int* __restrict__ deg) {
  const int i = blockIdx.x * blockDim.x + threadIdx.x;
  if (i >= N_EDGES + N_NODES) return;
  const int d = (i < N_EDGES) ? dst[i] : (i - N_EDGES);
  atomicAdd(&deg[d], 1);
}

// Shuffle-based single-block scan: 2 barriers per 1024-chunk instead of 20.
__global__ __launch_bounds__(1024) void scan_kernel(const int* __restrict__ deg,
                                                    int* __restrict__ rowp) {
  __shared__ int wsum[16];
  __shared__ int carry_s;
  const int t = threadIdx.x;
  const int lane = t & 63;
  const int w = t >> 6;
  if (t == 0) carry_s = 0;
  __syncthreads();
  for (int base = 0; base < N_NODES; base += 1024) {
    const int idx = base + t;
    const int v = (idx < N_NODES) ? deg[idx] : 0;
    int run = v;  // inclusive wave scan
#pragma unroll
    for (int off = 1; off < 64; off <<= 1) {
      const int u = __shfl_up(run, off);
      if (lane >= off) run += u;
    }
    if (lane == 63) wsum[w] = run;
    __syncthreads();
    if (w == 0) {
      int x = (lane < 16) ? wsum[lane] : 0;
#pragma unroll
      for (int off = 1; off < 16; off <<= 1) {
        const int u = __shfl_up(x, off);
        if (lane >= off) x += u;
      }
      if (lane < 16) wsum[lane] = x;  // inclusive over wave totals
    }
    __syncthreads();
    const int wpre = (w == 0) ? 0 : wsum[w - 1];
    const int c = carry_s;
    if (idx < N_NODES) rowp[idx] = c + wpre + run - v;  // exclusive
    __syncthreads();  // everyone read carry_s before update
    if (t == 1023) carry_s = c + wsum[15];
    __syncthreads();
  }
  if (t == 0) rowp[N_NODES] = carry_s;
}

__global__ __launch_bounds__(256) void scatter_kernel(
    const int* __restrict__ src, const int* __restrict__ dst,
    const int* __restrict__ rowp, int* __restrict__ fill,
    int* __restrict__ esrc) {
  const int i = blockIdx.x * blockDim.x + threadIdx.x;
  if (i >= N_EDGES + N_NODES) return;
  int s, d;
  if (i < N_EDGES) {
    s = src[i];
    d = dst[i];
  } else {
    s = d = i - N_EDGES;
  }
  const int pos = rowp[d] + atomicAdd(&fill[d], 1);
  esrc[pos] = s;
}

// ---------------------------------------------------------------------------
// Per-dst-node segment softmax + aggregation. One wave per node.
// Edge weights computed lane-parallel ONCE, cached in LDS (deg<=128 covers
// all nodes for this graph; correct tail path for larger). Serial accum loop
// reads LDS broadcasts (6 cyc) instead of global dependent chains (~400 cyc),
// 2-way unrolled with independent accumulators.
// ---------------------------------------------------------------------------
template <int F>
__global__ __launch_bounds__(256) void gat_aggregate(
    const int* __restrict__ rowp, const int* __restrict__ esrc,
    const float* __restrict__ h, const float* __restrict__ as_,
    const float* __restrict__ ad_, const float* __restrict__ b,
    float* __restrict__ out) {
  __shared__ float wc[4][128];
  __shared__ int sc[4][128];
  const int ws = threadIdx.x >> 6;
  const int wid = (blockIdx.x * blockDim.x + threadIdx.x) >> 6;
  const int lane = threadIdx.x & 63;
  if (wid >= N_NODES) return;
  const int start = rowp[wid], end = rowp[wid + 1];
  const float adv = ad_[wid];

  int s0 = 0, s1 = 0;
  float e0 = -1e30f, e1 = -1e30f;
  const int i0 = start + lane, i1 = start + 64 + lane;
  if (i0 < end) { s0 = esrc[i0]; e0 = leaky(as_[s0] + adv); }
  if (i1 < end) { s1 = esrc[i1]; e1 = leaky(as_[s1] + adv); }
  float m = fmaxf(e0, e1);
  for (int i = start + 128 + lane; i < end; i += 64)  // rare tail
    m = fmaxf(m, leaky(as_[esrc[i]] + adv));
#pragma unroll
  for (int off = 32; off; off >>= 1) m = fmaxf(m, __shfl_xor(m, off));

  const float w0 = (i0 < end) ? __expf(e0 - m) : 0.f;
  const float w1 = (i1 < end) ? __expf(e1 - m) : 0.f;
  float ssum = w0 + w1;
  for (int i = start + 128 + lane; i < end; i += 64)  // rare tail
    ssum += __expf(leaky(as_[esrc[i]] + adv) - m);
#pragma unroll
  for (int off = 32; off; off >>= 1) ssum += __shfl_xor(ssum, off);
  const float inv = 1.f / ssum;

  sc[ws][lane] = s0;
  sc[ws][lane + 64] = s1;
  wc[ws][lane] = w0;
  wc[ws][lane + 64] = w1;

  const int deg = end - start;
  const int ncached = deg < 128 ? deg : 128;
  float acc = 0.f, acc2 = 0.f;
  int j = 0;
  for (; j + 1 < ncached; j += 2) {
    const int t0 = sc[ws][j], t1 = sc[ws][j + 1];
    const float u0 = wc[ws][j], u1 = wc[ws][j + 1];
    if (lane < F) {
      acc += u0 * h[t0 * F + lane];
      acc2 += u1 * h[t1 * F + lane];
    }
  }
  for (; j < ncached; ++j)
    if (lane < F) acc += wc[ws][j] * h[sc[ws][j] * F + lane];
  for (int i = start + 128; i < end; ++i) {  // rare tail, recompute
    const int s = esrc[i];
    const float w = __expf(leaky(as_[s] + adv) - m);
    if (lane < F) acc += w * h[s * F + lane];
  }
  if (lane < F) {
    const float o = (acc + acc2) * inv + b[lane];
    out[wid * F + lane] = o > 0.f ? o : 0.f;
  }
}

// ---------------------------------------------------------------------------
// Decoder: out = sigmoid(z @ z^T), symmetric -> compute only bx<=by tiles,
// mirror-store the transpose. 128x128 tile, 256 threads, 8x8 per thread.
// ---------------------------------------------------------------------------
__global__ __launch_bounds__(256) void decoder_kernel(const float* __restrict__ z,
                                                      float* __restrict__ out) {
  const int bx = blockIdx.x, by = blockIdx.y;
  if (bx > by) return;  // upper-triangle blocks are mirrors
  __shared__ float At[40][132];
  __shared__ float Bt[40][132];
  const int i0 = by * 128;  // rows
  const int j0 = bx * 128;  // cols (j0 <= i0)
  const int t = threadIdx.x;

  for (int u = t; u < 1280; u += 256) {
    const int row = u / 10;
    const int kq = u - row * 10;
    int ga = i0 + row;
    ga = ga < N_NODES ? ga : N_NODES - 1;
    const float4 va = *(const float4*)(z + ga * 40 + kq * 4);
    At[kq * 4 + 0][row] = va.x;
    At[kq * 4 + 1][row] = va.y;
    At[kq * 4 + 2][row] = va.z;
    At[kq * 4 + 3][row] = va.w;
    int gb = j0 + row;
    gb = gb < N_NODES ? gb : N_NODES - 1;
    const float4 vb = *(const float4*)(z + gb * 40 + kq * 4);
    Bt[kq * 4 + 0][row] = vb.x;
    Bt[kq * 4 + 1][row] = vb.y;
    Bt[kq * 4 + 2][row] = vb.z;
    Bt[kq * 4 + 3][row] = vb.w;
  }
  __syncthreads();

  const int tx = t & 15, ty = t >> 4;
  float acc[8][8] = {};
  for (int k = 0; k < 40; ++k) {
    float a[8], b[8];
    *(float4*)&a[0] = *(const float4*)&At[k][ty * 8];
    *(float4*)&a[4] = *(const float4*)&At[k][ty * 8 + 4];
    *(float4*)&b[0] = *(const float4*)&Bt[k][tx * 8];
    *(float4*)&b[4] = *(const float4*)&Bt[k][tx * 8 + 4];
#pragma unroll
    for (int r = 0; r < 8; ++r)
#pragma unroll
      for (int c = 0; c < 8; ++c) acc[r][c] += a[r] * b[c];
  }

  // sigmoid in place
#pragma unroll
  for (int r = 0; r < 8; ++r)
#pragma unroll
    for (int c = 0; c < 8; ++c) acc[r][c] = 1.0f / (1.0f + __expf(-acc[r][c]));

  // normal store: rows gi = i0.., cols gj = j0..
#pragma unroll
  for (int r = 0; r < 8; ++r) {
    const int gi = i0 + ty * 8 + r;
    if (gi < N_NODES) {
      const int gj = j0 + tx * 8;
      float* dstp = out + (size_t)gi * N_NODES + gj;
      if (gj + 7 < N_NODES) {
        *(float4*)dstp = make_float4(acc[r][0], acc[r][1], acc[r][2], acc[r][3]);
        *(float4*)(dstp + 4) = make_float4(acc[r][4], acc[r][5], acc[r][6], acc[r][7]);
      } else {
#pragma unroll
        for (int c = 0; c < 8; ++c)
          if (gj + c < N_NODES) dstp[c] = acc[r][c];
      }
    }
  }

  // mirror store: rows j0.., cols i0..  (only off-diagonal blocks)
  if (bx < by) {
#pragma unroll
    for (int c = 0; c < 8; ++c) {
      const int gr = j0 + tx * 8 + c;  // < N guaranteed (j0 <= i0-128)
      const int ci = i0 + ty * 8;
      float* dstp = out + (size_t)gr * N_NODES + ci;
      if (ci + 7 < N_NODES) {
        *(float4*)dstp = make_float4(acc[0][c], acc[1][c], acc[2][c], acc[3][c]);
        *(float4*)(dstp + 4) = make_float4(acc[4][c], acc[5][c], acc[6][c], acc[7][c]);
      } else {
#pragma unroll
        for (int r = 0; r < 8; ++r)
          if (ci + r < N_NODES) dstp[r] = acc[r][c];
      }
    }
  }
}

// ---------------------------------------------------------------------------
extern "C" void kernel_launch(void* const* d_in, const int* in_sizes, int n_in,
                              void* d_out, int out_size, void* d_ws, size_t ws_size,
                              hipStream_t stream) {
  const float* x     = (const float*)d_in[0];
  const int*   ei    = (const int*)d_in[1];  // [2][E], int32 per harness contract
  const float* W1    = (const float*)d_in[2];
  const float* asrc1 = (const float*)d_in[3];
  const float* adst1 = (const float*)d_in[4];
  const float* b1    = (const float*)d_in[5];
  const float* W2    = (const float*)d_in[6];
  const float* asrc2 = (const float*)d_in[7];
  const float* adst2 = (const float*)d_in[8];
  const float* b2    = (const float*)d_in[9];
  float* out = (float*)d_out;

  // workspace layout (all 16B-aligned)
  float* wsp  = (float*)d_ws;
  float* h1   = wsp;             // N*50
  float* out1 = h1 + 600000;     // N*50
  float* h2   = out1 + 600000;   // N*40
  float* z    = h2 + 480000;     // N*40
  float* as_  = z + 480000;      // N
  float* ad_  = as_ + 12000;     // N
  int* deg  = (int*)(ad_ + 12000);  // N   \ adjacent: one memset
  int* fill = deg + 12000;          // N   /
  int* rowp = fill + 12000;         // N+1
  int* esrc = rowp + 12001;         // E+N

  const int* src = ei;
  const int* dst = ei + N_EDGES;

  hipMemsetAsync(deg, 0, 2 * N_NODES * sizeof(int), stream);  // deg + fill

  const int eb = (N_EDGES + N_NODES + 255) / 256;
  histo_kernel<<<eb, 256, 0, stream>>>(dst, deg);
  scan_kernel<<<1, 1024, 0, stream>>>(deg, rowp);
  scatter_kernel<<<eb, 256, 0, stream>>>(src, dst, rowp, fill, esrc);

  const int nb = (N_NODES + 255) / 256;
  node_linear<40, 50><<<nb, 256, 0, stream>>>(x, W1, asrc1, adst1, h1, as_, ad_);
  gat_aggregate<50><<<3000, 256, 0, stream>>>(rowp, esrc, h1, as_, ad_, b1, out1);
  node_linear<50, 40><<<nb, 256, 0, stream>>>(out1, W2, asrc2, adst2, h2, as_, ad_);
  gat_aggregate<40><<<3000, 256, 0, stream>>>(rowp, esrc, h2, as_, ad_, b2, z);

  dim3 dgrid(94, 94);
  decoder_kernel<<<dgrid, 256, 0, stream>>>(z, out);
}